// Round 3
// baseline (398.330 us; speedup 1.0000x reference)
//
#include <hip/hip_runtime.h>
#include <hip/hip_bf16.h>
#include <cstddef>
#include <math.h>

// ---------------------------------------------------------------------------
// Model constants
// ---------------------------------------------------------------------------
#define S_LEN 1024
#define D_DIM 128
#define H_HEADS 8
#define DH_DIM 16
#define FF_DIM 2048
#define L_LAYERS 4
#define HID_DIM 768
#define LN_EPS 1e-5f

#define KSPLIT 8
#define KCH (S_LEN / KSPLIT)     // 128 keys per chunk

typedef __attribute__((ext_vector_type(8))) short bf16x8;   // 8 bf16 in 4 VGPRs
typedef __attribute__((ext_vector_type(4))) float f32x4;

// ---------------------------------------------------------------------------
// Kernel: embeddings + motion MLP + focus linear + positional -> x (f32+bf16)
// ---------------------------------------------------------------------------
__global__ __launch_bounds__(128) void embed_kernel(
    const int* __restrict__ shot, const int* __restrict__ cam,
    const int* __restrict__ light, const int* __restrict__ tone,
    const int* __restrict__ rhythm, const int* __restrict__ trans,
    const float* __restrict__ motion, const float* __restrict__ focus,
    const float* __restrict__ E_shot, const float* __restrict__ E_cam,
    const float* __restrict__ E_light, const float* __restrict__ E_tone,
    const float* __restrict__ E_rhythm, const float* __restrict__ E_trans,
    const float* __restrict__ W_m1, const float* __restrict__ b_m1,
    const float* __restrict__ W_m2, const float* __restrict__ b_m2,
    const float* __restrict__ W_f, const float* __restrict__ b_f,
    const float* __restrict__ pos, float* __restrict__ x,
    __hip_bfloat16* __restrict__ x_bf)
{
    const int s = blockIdx.x;
    const int d = threadIdx.x;           // 0..127

    const float m0 = motion[s * 4 + 0];
    const float m1 = motion[s * 4 + 1];
    const float m2 = motion[s * 4 + 2];
    const float m3 = motion[s * 4 + 3];
    const float f0 = focus[s * 2 + 0];
    const float f1 = focus[s * 2 + 1];

    __shared__ float h[64];
    if (d < 64) {
        float a = b_m1[d];
        a += W_m1[d * 4 + 0] * m0;
        a += W_m1[d * 4 + 1] * m1;
        a += W_m1[d * 4 + 2] * m2;
        a += W_m1[d * 4 + 3] * m3;
        h[d] = fmaxf(a, 0.0f);
    }
    __syncthreads();

    float acc = b_m2[d];
    const float* wrow = W_m2 + (size_t)d * 64;
    #pragma unroll
    for (int k = 0; k < 64; k += 4) {
        float4 w4 = *reinterpret_cast<const float4*>(wrow + k);
        acc += w4.x * h[k] + w4.y * h[k + 1] + w4.z * h[k + 2] + w4.w * h[k + 3];
    }

    acc += b_f[d] + W_f[d * 2 + 0] * f0 + W_f[d * 2 + 1] * f1;

    acc += E_shot  [(size_t)shot[s]   * D_DIM + d];
    acc += E_cam   [(size_t)cam[s]    * D_DIM + d];
    acc += E_light [(size_t)light[s]  * D_DIM + d];
    acc += E_tone  [(size_t)tone[s]   * D_DIM + d];
    acc += E_rhythm[(size_t)rhythm[s] * D_DIM + d];
    acc += E_trans [(size_t)trans[s]  * D_DIM + d];

    acc += pos[(size_t)s * D_DIM + d];

    const size_t idx = (size_t)s * D_DIM + d;
    x[idx] = acc;
    x_bf[idx] = __float2bfloat16(acc);
}

// ---------------------------------------------------------------------------
// One-shot weight conversion fp32 -> bf16, concatenated layout:
//   [Wqkv 196608][Wo 65536][W1 1048576][W2 1048576][W_out 98304]  (bf16 elems)
// Each thread converts 4 elems (one float4). grid 2400 x 256.
// ---------------------------------------------------------------------------
__global__ __launch_bounds__(256) void wconv_kernel(
    const float* __restrict__ Wqkv, const float* __restrict__ Wo,
    const float* __restrict__ W1, const float* __restrict__ W2,
    const float* __restrict__ Wout, __hip_bfloat16* __restrict__ dst)
{
    const int i = blockIdx.x * 256 + threadIdx.x;   // float4 index, 0..614399
    const float* src;
    int off4;
    if (i < 49152)       { src = Wqkv; off4 = i; }
    else if (i < 65536)  { src = Wo;   off4 = i - 49152; }
    else if (i < 327680) { src = W1;   off4 = i - 65536; }
    else if (i < 589824) { src = W2;   off4 = i - 327680; }
    else                 { src = Wout; off4 = i - 589824; }
    const float4 v = reinterpret_cast<const float4*>(src)[off4];
    __hip_bfloat16* o = dst + (size_t)i * 4;
    o[0] = __float2bfloat16(v.x);
    o[1] = __float2bfloat16(v.y);
    o[2] = __float2bfloat16(v.z);
    o[3] = __float2bfloat16(v.w);
}

// ---------------------------------------------------------------------------
// MFMA GEMM: C[M,N] = A[M,K] @ W[N,K]^T + bias.  A,W bf16 row-major (K-major).
// v_mfma_f32_16x16x32_bf16, fragments loaded straight from global (L1/L2-
// resident operands; A-frag = 16B at row (l&15), k-offset (l>>4)*8).
// Block 256 = 4 waves; tile 64(M) x 64(N); wave w owns rows [16w,16w+16).
// grid (N/64, M/64). K multiple of 32.
// ---------------------------------------------------------------------------
template<int RELU, int OUT_BF>
__global__ __launch_bounds__(256) void gemm_mfma_kernel(
    const __hip_bfloat16* __restrict__ A, const __hip_bfloat16* __restrict__ W,
    const float* __restrict__ bias, __hip_bfloat16* __restrict__ Cb,
    float* __restrict__ Cf, int N, int K)
{
    const int t = threadIdx.x;
    const int w  = t >> 6;
    const int l  = t & 63;
    const int lr = l & 15;
    const int lk = (l >> 4) * 8;
    const int m0 = blockIdx.y * 64 + w * 16;
    const int n0 = blockIdx.x * 64;

    f32x4 acc[4] = {};

    const __hip_bfloat16* Ap = A + (size_t)(m0 + lr) * K + lk;
    const __hip_bfloat16* Wp = W + (size_t)(n0 + lr) * K + lk;

    #pragma unroll 4
    for (int k = 0; k < K; k += 32) {
        const bf16x8 a = *reinterpret_cast<const bf16x8*>(Ap + k);
        #pragma unroll
        for (int nt = 0; nt < 4; ++nt) {
            const bf16x8 b = *reinterpret_cast<const bf16x8*>(Wp + (size_t)nt * 16 * K + k);
            acc[nt] = __builtin_amdgcn_mfma_f32_16x16x32_bf16(a, b, acc[nt], 0, 0, 0);
        }
    }

    const int orow = m0 + (l >> 4) * 4;     // C/D layout: row=(l>>4)*4+j, col=l&15
    #pragma unroll
    for (int nt = 0; nt < 4; ++nt) {
        const int col = n0 + nt * 16 + lr;
        const float bv = bias[col];
        #pragma unroll
        for (int j = 0; j < 4; ++j) {
            float v = acc[nt][j] + bv;
            if (RELU) v = fmaxf(v, 0.f);
            if (OUT_BF) Cb[(size_t)(orow + j) * N + col] = __float2bfloat16(v);
            else        Cf[(size_t)(orow + j) * N + col] = v;
        }
    }
}

// ---------------------------------------------------------------------------
// Fused MFMA GEMM (N=128) + residual add + LayerNorm.
//   x = LN(x + A @ W^T + bias) * g + b ; writes x (f32) and x_bf (bf16).
// Block 512 = 8 waves. M-tile 32. wave w: rows 16*(w&1), cols 32*(w>>1).
// grid M/32. K multiple of 32 (128 for Wo, 2048 for FF2).
// ---------------------------------------------------------------------------
__global__ __launch_bounds__(512) void gemm_ln_kernel(
    const __hip_bfloat16* __restrict__ A, const __hip_bfloat16* __restrict__ W,
    const float* __restrict__ bias, float* __restrict__ x,
    __hip_bfloat16* __restrict__ x_bf,
    const float* __restrict__ g, const float* __restrict__ b, int K)
{
    __shared__ float tile[32][132];

    const int t = threadIdx.x;
    const int w  = t >> 6;
    const int l  = t & 63;
    const int lr = l & 15;
    const int lk = (l >> 4) * 8;
    const int mb = blockIdx.x * 32;
    const int mw = (w & 1) * 16;
    const int nb = (w >> 1) * 32;

    f32x4 acc[2] = {};

    const __hip_bfloat16* Ap = A + (size_t)(mb + mw + lr) * K + lk;
    const __hip_bfloat16* Wp = W + (size_t)(nb + lr) * K + lk;

    #pragma unroll 4
    for (int k = 0; k < K; k += 32) {
        const bf16x8 a = *reinterpret_cast<const bf16x8*>(Ap + k);
        #pragma unroll
        for (int nt = 0; nt < 2; ++nt) {
            const bf16x8 bb = *reinterpret_cast<const bf16x8*>(Wp + (size_t)nt * 16 * K + k);
            acc[nt] = __builtin_amdgcn_mfma_f32_16x16x32_bf16(a, bb, acc[nt], 0, 0, 0);
        }
    }

    const int rloc = mw + (l >> 4) * 4;
    #pragma unroll
    for (int nt = 0; nt < 2; ++nt) {
        const int col = nb + nt * 16 + lr;
        const float bv = bias[col];
        #pragma unroll
        for (int j = 0; j < 4; ++j)
            tile[rloc + j][col] = acc[nt][j] + bv;
    }
    __syncthreads();

    // LN phase: 512 threads, 16 per row, 8 cols each.
    const int row = t >> 4;        // 0..31
    const int sub = t & 15;
    const size_t gbase = (size_t)(mb + row) * D_DIM + sub * 8;

    float v[8];
    #pragma unroll
    for (int j = 0; j < 8; ++j) v[j] = tile[row][sub * 8 + j] + x[gbase + j];

    float s = 0.f;
    #pragma unroll
    for (int j = 0; j < 8; ++j) s += v[j];
    s += __shfl_xor(s, 1); s += __shfl_xor(s, 2);
    s += __shfl_xor(s, 4); s += __shfl_xor(s, 8);
    const float mu = s * (1.0f / 128.0f);

    float qs = 0.f;
    #pragma unroll
    for (int j = 0; j < 8; ++j) { const float dd = v[j] - mu; qs += dd * dd; }
    qs += __shfl_xor(qs, 1); qs += __shfl_xor(qs, 2);
    qs += __shfl_xor(qs, 4); qs += __shfl_xor(qs, 8);
    const float rs = rsqrtf(qs * (1.0f / 128.0f) + LN_EPS);

    #pragma unroll
    for (int j = 0; j < 8; ++j) {
        const int c = sub * 8 + j;
        const float r = (v[j] - mu) * rs * g[c] + b[c];
        x[gbase + j] = r;
        x_bf[gbase + j] = __float2bfloat16(r);
    }
}

// ---------------------------------------------------------------------------
// Attention, split-K flash style (bf16 qkv input, fp32 math).
// grid (KSPLIT, S/256, H), block 256. Lane owns one q row; K/V chunk in LDS.
// ---------------------------------------------------------------------------
__global__ __launch_bounds__(256) void attn_part_kernel(
    const __hip_bfloat16* __restrict__ qkv,
    float* __restrict__ pm, float* __restrict__ pl, float* __restrict__ po)
{
    __shared__ float Ks[KCH * 16];
    __shared__ float Vs[KCH * 16];

    const int t     = threadIdx.x;
    const int chunk = blockIdx.x;
    const int qb    = blockIdx.y;
    const int head  = blockIdx.z;
    const int kbase = chunk * KCH;

    // stage K,V chunk (convert bf16 -> f32): thread t does 8 elems of each
    {
        const int row  = t >> 1;
        const int half = (t & 1) * 8;
        const __hip_bfloat16* src = qkv + (size_t)(kbase + row) * 384 + head * 16 + half;
        #pragma unroll
        for (int j = 0; j < 8; ++j)
            Ks[row * 16 + half + j] = __bfloat162float(src[128 + j]);
        #pragma unroll
        for (int j = 0; j < 8; ++j)
            Vs[row * 16 + half + j] = __bfloat162float(src[256 + j]);
    }

    // own q row, pre-scaled
    const int qrow = qb * 256 + t;
    float q[16];
    {
        const __hip_bfloat16* qp = qkv + (size_t)qrow * 384 + head * 16;
        #pragma unroll
        for (int d = 0; d < 16; ++d)
            q[d] = __bfloat162float(qp[d]) * 0.25f;
    }
    __syncthreads();

    float m = -INFINITY, l = 0.f;
    float O[16];
    #pragma unroll
    for (int d = 0; d < 16; ++d) O[d] = 0.f;

    for (int j0 = 0; j0 < KCH; j0 += 8) {
        float s[8];
        #pragma unroll
        for (int jj = 0; jj < 8; ++jj) {
            const float* kr = &Ks[(j0 + jj) * 16];
            float a = 0.f;
            #pragma unroll
            for (int d = 0; d < 16; d += 4) {
                float4 kv = *reinterpret_cast<const float4*>(kr + d);
                a += q[d] * kv.x + q[d + 1] * kv.y + q[d + 2] * kv.z + q[d + 3] * kv.w;
            }
            s[jj] = a;
        }
        float bm = s[0];
        #pragma unroll
        for (int jj = 1; jj < 8; ++jj) bm = fmaxf(bm, s[jj]);
        const float mn = fmaxf(m, bm);
        const float corr = __expf(m - mn);
        m = mn;
        l *= corr;
        #pragma unroll
        for (int d = 0; d < 16; ++d) O[d] *= corr;
        #pragma unroll
        for (int jj = 0; jj < 8; ++jj) {
            const float p = __expf(s[jj] - m);
            l += p;
            const float* vr = &Vs[(j0 + jj) * 16];
            #pragma unroll
            for (int d = 0; d < 16; ++d) O[d] += p * vr[d];
        }
    }

    const int pidx = ((chunk * H_HEADS + head) << 10) + qrow;
    pm[pidx] = m;
    pl[pidx] = l;
    #pragma unroll
    for (int d = 0; d < 16; d += 4) {
        float4 v = make_float4(O[d], O[d + 1], O[d + 2], O[d + 3]);
        *reinterpret_cast<float4*>(&po[(size_t)pidx * 16 + d]) = v;
    }
}

// combine partials -> attn_bf [S, D] (bf16)
__global__ __launch_bounds__(256) void attn_comb_kernel(
    const float* __restrict__ pm, const float* __restrict__ pl,
    const float* __restrict__ po, __hip_bfloat16* __restrict__ o)
{
    const int gid  = blockIdx.x * 256 + threadIdx.x;   // 0..8191
    const int head = gid >> 10;
    const int row  = gid & 1023;

    float mg = -INFINITY;
    #pragma unroll
    for (int c = 0; c < KSPLIT; ++c)
        mg = fmaxf(mg, pm[((c * H_HEADS + head) << 10) + row]);

    float lg = 0.f;
    float O[16];
    #pragma unroll
    for (int d = 0; d < 16; ++d) O[d] = 0.f;

    #pragma unroll
    for (int c = 0; c < KSPLIT; ++c) {
        const int pidx = ((c * H_HEADS + head) << 10) + row;
        const float w = __expf(pm[pidx] - mg);
        lg += pl[pidx] * w;
        #pragma unroll
        for (int d = 0; d < 16; d += 4) {
            float4 v = *reinterpret_cast<const float4*>(&po[(size_t)pidx * 16 + d]);
            O[d] += w * v.x; O[d + 1] += w * v.y;
            O[d + 2] += w * v.z; O[d + 3] += w * v.w;
        }
    }

    const float inv = 1.f / lg;
    __hip_bfloat16* op = o + (size_t)row * D_DIM + head * 16;
    #pragma unroll
    for (int d = 0; d < 16; ++d)
        op[d] = __float2bfloat16(O[d] * inv);
}

__global__ void zero_kernel(float* __restrict__ p, int n)
{
    const int i = blockIdx.x * blockDim.x + threadIdx.x;
    if (i < n) p[i] = 0.0f;
}

// ---------------------------------------------------------------------------
// Host launch
// ---------------------------------------------------------------------------
extern "C" void kernel_launch(void* const* d_in, const int* in_sizes, int n_in,
                              void* d_out, int out_size, void* d_ws, size_t ws_size,
                              hipStream_t stream)
{
    const int*   shot    = (const int*)  d_in[0];
    const int*   cam     = (const int*)  d_in[1];
    const int*   light   = (const int*)  d_in[2];
    const int*   tone    = (const int*)  d_in[3];
    const int*   rhythm  = (const int*)  d_in[4];
    const int*   trans   = (const int*)  d_in[5];
    const float* motion  = (const float*)d_in[6];
    const float* focus   = (const float*)d_in[7];
    const float* E_shot  = (const float*)d_in[8];
    const float* E_cam   = (const float*)d_in[9];
    const float* E_light = (const float*)d_in[10];
    const float* E_tone  = (const float*)d_in[11];
    const float* E_rhyth = (const float*)d_in[12];
    const float* E_trans = (const float*)d_in[13];
    const float* W_m1    = (const float*)d_in[14];
    const float* b_m1    = (const float*)d_in[15];
    const float* W_m2    = (const float*)d_in[16];
    const float* b_m2    = (const float*)d_in[17];
    const float* W_f     = (const float*)d_in[18];
    const float* b_f     = (const float*)d_in[19];
    const float* pos     = (const float*)d_in[20];
    const float* Wqkv    = (const float*)d_in[21];
    const float* bqkv    = (const float*)d_in[22];
    const float* Wo      = (const float*)d_in[23];
    const float* bo      = (const float*)d_in[24];
    const float* W1      = (const float*)d_in[25];
    const float* b1      = (const float*)d_in[26];
    const float* W2      = (const float*)d_in[27];
    const float* b2      = (const float*)d_in[28];
    const float* ln1_g   = (const float*)d_in[29];
    const float* ln1_b   = (const float*)d_in[30];
    const float* ln2_g   = (const float*)d_in[31];
    const float* ln2_b   = (const float*)d_in[32];
    const float* W_out   = (const float*)d_in[33];
    const float* b_out   = (const float*)d_in[34];

    float* out = (float*)d_out;

    // workspace layout
    float* ws = (float*)d_ws;
    float* x  = ws;                       // 131072 f32
    float* pm = x  + S_LEN * D_DIM;       // 65536
    float* pl = pm + KSPLIT * H_HEADS * S_LEN;     // 65536
    float* po = pl + KSPLIT * H_HEADS * S_LEN;     // 1048576
    __hip_bfloat16* bfb = (__hip_bfloat16*)(po + KSPLIT * H_HEADS * S_LEN * 16);
    __hip_bfloat16* wbf     = bfb;                    // 2457600 bf16 (weights)
    __hip_bfloat16* wqkv_bf = wbf;                    // [4][384][128]
    __hip_bfloat16* wo_bf   = wqkv_bf + 196608;       // [4][128][128]
    __hip_bfloat16* w1_bf   = wo_bf   + 65536;        // [4][2048][128]
    __hip_bfloat16* w2_bf   = w1_bf   + 1048576;      // [4][128][2048]
    __hip_bfloat16* wout_bf = w2_bf   + 1048576;      // [768][128]
    __hip_bfloat16* x_bf    = wout_bf + 98304;        // [1024][128]
    __hip_bfloat16* qkv_bf  = x_bf    + 131072;       // [1024][384]
    __hip_bfloat16* attn_bf = qkv_bf  + 393216;       // [1024][128]
    __hip_bfloat16* hbuf_bf = attn_bf + 131072;       // [1024][2048]

    embed_kernel<<<S_LEN, 128, 0, stream>>>(
        shot, cam, light, tone, rhythm, trans, motion, focus,
        E_shot, E_cam, E_light, E_tone, E_rhyth, E_trans,
        W_m1, b_m1, W_m2, b_m2, W_f, b_f, pos, x, x_bf);

    wconv_kernel<<<2400, 256, 0, stream>>>(Wqkv, Wo, W1, W2, W_out, wbf);

    for (int i = 0; i < L_LAYERS; ++i) {
        const __hip_bfloat16* Wqkv_i = wqkv_bf + (size_t)i * 3 * D_DIM * D_DIM;
        const __hip_bfloat16* Wo_i   = wo_bf   + (size_t)i * D_DIM * D_DIM;
        const __hip_bfloat16* W1_i   = w1_bf   + (size_t)i * FF_DIM * D_DIM;
        const __hip_bfloat16* W2_i   = w2_bf   + (size_t)i * D_DIM * FF_DIM;
        const float* bqkv_i = bqkv + (size_t)i * 3 * D_DIM;
        const float* bo_i   = bo   + (size_t)i * D_DIM;
        const float* b1_i   = b1   + (size_t)i * FF_DIM;
        const float* b2_i   = b2   + (size_t)i * D_DIM;

        // qkv = x @ Wqkv^T + bqkv  -> bf16 [1024, 384]
        gemm_mfma_kernel<0, 1><<<dim3(384 / 64, S_LEN / 64), 256, 0, stream>>>(
            x_bf, Wqkv_i, bqkv_i, qkv_bf, nullptr, 384, 128);

        // attention (split-K partials + combine) -> bf16 [1024, 128]
        attn_part_kernel<<<dim3(KSPLIT, S_LEN / 256, H_HEADS), 256, 0, stream>>>(
            qkv_bf, pm, pl, po);
        attn_comb_kernel<<<dim3(S_LEN * H_HEADS / 256), 256, 0, stream>>>(
            pm, pl, po, attn_bf);

        // x = LN(x + attn @ Wo^T + bo)  (fused)
        gemm_ln_kernel<<<dim3(S_LEN / 32), 512, 0, stream>>>(
            attn_bf, Wo_i, bo_i, x, x_bf,
            ln1_g + (size_t)i * D_DIM, ln1_b + (size_t)i * D_DIM, 128);

        // h = relu(x @ W1^T + b1) -> bf16 [1024, 2048]
        gemm_mfma_kernel<1, 1><<<dim3(FF_DIM / 64, S_LEN / 64), 256, 0, stream>>>(
            x_bf, W1_i, b1_i, hbuf_bf, nullptr, FF_DIM, 128);

        // x = LN(x + h @ W2^T + b2)  (fused, K=2048)
        gemm_ln_kernel<<<dim3(S_LEN / 32), 512, 0, stream>>>(
            hbuf_bf, W2_i, b2_i, x, x_bf,
            ln2_g + (size_t)i * D_DIM, ln2_b + (size_t)i * D_DIM, FF_DIM);
    }

    // cond = x @ W_out^T + b_out  -> f32 [1024, 768]
    gemm_mfma_kernel<0, 0><<<dim3(HID_DIM / 64, S_LEN / 64), 256, 0, stream>>>(
        x_bf, wout_bf, b_out, nullptr, out, HID_DIM, 128);

    // boundary_mask = zeros [1024]
    zero_kernel<<<1, 1024, 0, stream>>>(out + (size_t)S_LEN * HID_DIM, S_LEN);
}

// Round 4
// 252.991 us; speedup vs baseline: 1.5745x; 1.5745x over previous
//
#include <hip/hip_runtime.h>
#include <hip/hip_bf16.h>
#include <cstddef>
#include <math.h>

// ---------------------------------------------------------------------------
// Model constants
// ---------------------------------------------------------------------------
#define S_LEN 1024
#define D_DIM 128
#define H_HEADS 8
#define DH_DIM 16
#define FF_DIM 2048
#define L_LAYERS 4
#define HID_DIM 768
#define LN_EPS 1e-5f

#define KSPLIT 8
#define KCH (S_LEN / KSPLIT)     // 128 keys per chunk

typedef __attribute__((ext_vector_type(8))) short bf16x8;   // 8 bf16 in 4 VGPRs
typedef __attribute__((ext_vector_type(4))) float f32x4;

// ---------------------------------------------------------------------------
// Kernel: embeddings + motion MLP + focus linear + positional -> x (f32+bf16)
// ---------------------------------------------------------------------------
__global__ __launch_bounds__(128) void embed_kernel(
    const int* __restrict__ shot, const int* __restrict__ cam,
    const int* __restrict__ light, const int* __restrict__ tone,
    const int* __restrict__ rhythm, const int* __restrict__ trans,
    const float* __restrict__ motion, const float* __restrict__ focus,
    const float* __restrict__ E_shot, const float* __restrict__ E_cam,
    const float* __restrict__ E_light, const float* __restrict__ E_tone,
    const float* __restrict__ E_rhythm, const float* __restrict__ E_trans,
    const float* __restrict__ W_m1, const float* __restrict__ b_m1,
    const float* __restrict__ W_m2, const float* __restrict__ b_m2,
    const float* __restrict__ W_f, const float* __restrict__ b_f,
    const float* __restrict__ pos, float* __restrict__ x,
    __hip_bfloat16* __restrict__ x_bf)
{
    const int s = blockIdx.x;
    const int d = threadIdx.x;           // 0..127

    const float m0 = motion[s * 4 + 0];
    const float m1 = motion[s * 4 + 1];
    const float m2 = motion[s * 4 + 2];
    const float m3 = motion[s * 4 + 3];
    const float f0 = focus[s * 2 + 0];
    const float f1 = focus[s * 2 + 1];

    __shared__ float h[64];
    if (d < 64) {
        float a = b_m1[d];
        a += W_m1[d * 4 + 0] * m0;
        a += W_m1[d * 4 + 1] * m1;
        a += W_m1[d * 4 + 2] * m2;
        a += W_m1[d * 4 + 3] * m3;
        h[d] = fmaxf(a, 0.0f);
    }
    __syncthreads();

    float acc = b_m2[d];
    const float* wrow = W_m2 + (size_t)d * 64;
    #pragma unroll
    for (int k = 0; k < 64; k += 4) {
        float4 w4 = *reinterpret_cast<const float4*>(wrow + k);
        acc += w4.x * h[k] + w4.y * h[k + 1] + w4.z * h[k + 2] + w4.w * h[k + 3];
    }

    acc += b_f[d] + W_f[d * 2 + 0] * f0 + W_f[d * 2 + 1] * f1;

    acc += E_shot  [(size_t)shot[s]   * D_DIM + d];
    acc += E_cam   [(size_t)cam[s]    * D_DIM + d];
    acc += E_light [(size_t)light[s]  * D_DIM + d];
    acc += E_tone  [(size_t)tone[s]   * D_DIM + d];
    acc += E_rhythm[(size_t)rhythm[s] * D_DIM + d];
    acc += E_trans [(size_t)trans[s]  * D_DIM + d];

    acc += pos[(size_t)s * D_DIM + d];

    const size_t idx = (size_t)s * D_DIM + d;
    x[idx] = acc;
    x_bf[idx] = __float2bfloat16(acc);
}

// ---------------------------------------------------------------------------
// One-shot weight conversion fp32 -> bf16, concatenated layout:
//   [Wqkv 196608][Wo 65536][W1 1048576][W2 1048576][W_out 98304]  (bf16 elems)
// ---------------------------------------------------------------------------
__global__ __launch_bounds__(256) void wconv_kernel(
    const float* __restrict__ Wqkv, const float* __restrict__ Wo,
    const float* __restrict__ W1, const float* __restrict__ W2,
    const float* __restrict__ Wout, __hip_bfloat16* __restrict__ dst)
{
    const int i = blockIdx.x * 256 + threadIdx.x;   // float4 index, 0..614399
    const float* src;
    int off4;
    if (i < 49152)       { src = Wqkv; off4 = i; }
    else if (i < 65536)  { src = Wo;   off4 = i - 49152; }
    else if (i < 327680) { src = W1;   off4 = i - 65536; }
    else if (i < 589824) { src = W2;   off4 = i - 327680; }
    else                 { src = Wout; off4 = i - 589824; }
    const float4 v = reinterpret_cast<const float4*>(src)[off4];
    __hip_bfloat16* o = dst + (size_t)i * 4;
    o[0] = __float2bfloat16(v.x);
    o[1] = __float2bfloat16(v.y);
    o[2] = __float2bfloat16(v.z);
    o[3] = __float2bfloat16(v.w);
}

// ---------------------------------------------------------------------------
// Direct MFMA GEMM: C[M,N] = A[M,K] @ W[N,K]^T + bias.  bf16 in, K-major both.
// Block 256 = 4 waves in 2x2: wave w covers rows (w&1)*16, cols (w>>1)*32 of a
// 32x64 block tile. grid (N/64, M/32). Operands L1/L2-resident; loads direct
// from global (verified m89/m91 fragment layout).
// ---------------------------------------------------------------------------
template<int RELU, int OUT_BF>
__global__ __launch_bounds__(256) void gemm_mfma_kernel(
    const __hip_bfloat16* __restrict__ A, const __hip_bfloat16* __restrict__ W,
    const float* __restrict__ bias, __hip_bfloat16* __restrict__ Cb,
    float* __restrict__ Cf, int N, int K)
{
    const int t = threadIdx.x;
    const int w  = t >> 6;
    const int l  = t & 63;
    const int lr = l & 15;
    const int lk = (l >> 4) * 8;
    const int m0 = blockIdx.y * 32 + (w & 1) * 16;
    const int n0 = blockIdx.x * 64 + (w >> 1) * 32;

    f32x4 acc[2] = {};

    const __hip_bfloat16* Ap = A + (size_t)(m0 + lr) * K + lk;
    const __hip_bfloat16* Wp = W + (size_t)(n0 + lr) * K + lk;

    #pragma unroll 4
    for (int k = 0; k < K; k += 32) {
        const bf16x8 a = *reinterpret_cast<const bf16x8*>(Ap + k);
        #pragma unroll
        for (int nt = 0; nt < 2; ++nt) {
            const bf16x8 b = *reinterpret_cast<const bf16x8*>(Wp + (size_t)nt * 16 * K + k);
            acc[nt] = __builtin_amdgcn_mfma_f32_16x16x32_bf16(a, b, acc[nt], 0, 0, 0);
        }
    }

    const int orow = m0 + (l >> 4) * 4;     // C/D: row=(l>>4)*4+j, col=l&15
    #pragma unroll
    for (int nt = 0; nt < 2; ++nt) {
        const int col = n0 + nt * 16 + lr;
        const float bv = bias[col];
        #pragma unroll
        for (int j = 0; j < 4; ++j) {
            float v = acc[nt][j] + bv;
            if (RELU) v = fmaxf(v, 0.f);
            if (OUT_BF) Cb[(size_t)(orow + j) * N + col] = __float2bfloat16(v);
            else        Cf[(size_t)(orow + j) * N + col] = v;
        }
    }
}

// ---------------------------------------------------------------------------
// Split-K MFMA GEMM: P[z][M,N] partial = A[:,kz] @ W[:,kz]^T (f32, no bias).
// Same 2x2 wave tiling; grid (N/64, M/32, KS); k-chunk = KC elements.
// ---------------------------------------------------------------------------
__global__ __launch_bounds__(256) void gemm_sk_kernel(
    const __hip_bfloat16* __restrict__ A, const __hip_bfloat16* __restrict__ W,
    float* __restrict__ P, int N, int K, int KC)
{
    const int t = threadIdx.x;
    const int w  = t >> 6;
    const int l  = t & 63;
    const int lr = l & 15;
    const int lk = (l >> 4) * 8;
    const int m0 = blockIdx.y * 32 + (w & 1) * 16;
    const int n0 = blockIdx.x * 64 + (w >> 1) * 32;
    const int kbeg = blockIdx.z * KC;

    f32x4 acc[2] = {};

    const __hip_bfloat16* Ap = A + (size_t)(m0 + lr) * K + lk + kbeg;
    const __hip_bfloat16* Wp = W + (size_t)(n0 + lr) * K + lk + kbeg;

    #pragma unroll 4
    for (int k = 0; k < KC; k += 32) {
        const bf16x8 a = *reinterpret_cast<const bf16x8*>(Ap + k);
        #pragma unroll
        for (int nt = 0; nt < 2; ++nt) {
            const bf16x8 b = *reinterpret_cast<const bf16x8*>(Wp + (size_t)nt * 16 * K + k);
            acc[nt] = __builtin_amdgcn_mfma_f32_16x16x32_bf16(a, b, acc[nt], 0, 0, 0);
        }
    }

    float* Pz = P + (size_t)blockIdx.z * S_LEN * N;
    const int orow = m0 + (l >> 4) * 4;
    #pragma unroll
    for (int nt = 0; nt < 2; ++nt) {
        const int col = n0 + nt * 16 + lr;
        #pragma unroll
        for (int j = 0; j < 4; ++j)
            Pz[(size_t)(orow + j) * N + col] = acc[nt][j];
    }
}

// ---------------------------------------------------------------------------
// x = LN(x + sum_p c[p] + bias) * g + b ; writes x (f32) and x_bf (bf16).
// grid S, 128 threads.
// ---------------------------------------------------------------------------
__global__ __launch_bounds__(128) void add_ln_kernel(
    float* __restrict__ x, __hip_bfloat16* __restrict__ x_bf,
    const float* __restrict__ c, int nparts, int pstride,
    const float* __restrict__ bias,
    const float* __restrict__ g, const float* __restrict__ b)
{
    const int srow = blockIdx.x;
    const int d = threadIdx.x;
    const size_t idx = (size_t)srow * D_DIM + d;

    float v = x[idx];
    for (int p = 0; p < nparts; ++p) v += c[idx + (size_t)p * pstride];
    if (bias) v += bias[d];

    __shared__ float red[2];
    const int wv = d >> 6, ln = d & 63;

    float sum = v;
    #pragma unroll
    for (int off = 32; off >= 1; off >>= 1) sum += __shfl_xor(sum, off);
    if (ln == 0) red[wv] = sum;
    __syncthreads();
    const float mu = (red[0] + red[1]) * (1.0f / 128.0f);

    const float dv = v - mu;
    float sq = dv * dv;
    #pragma unroll
    for (int off = 32; off >= 1; off >>= 1) sq += __shfl_xor(sq, off);
    __syncthreads();
    if (ln == 0) red[wv] = sq;
    __syncthreads();
    const float var = (red[0] + red[1]) * (1.0f / 128.0f);

    const float r = dv * rsqrtf(var + LN_EPS) * g[d] + b[d];
    x[idx] = r;
    x_bf[idx] = __float2bfloat16(r);
}

// ---------------------------------------------------------------------------
// Attention, split-K flash style (bf16 qkv input, fp32 math).
// grid (KSPLIT, S/256, H), block 256. Lane owns one q row; K/V chunk in LDS.
// ---------------------------------------------------------------------------
__global__ __launch_bounds__(256) void attn_part_kernel(
    const __hip_bfloat16* __restrict__ qkv,
    float* __restrict__ pm, float* __restrict__ pl, float* __restrict__ po)
{
    __shared__ float Ks[KCH * 16];
    __shared__ float Vs[KCH * 16];

    const int t     = threadIdx.x;
    const int chunk = blockIdx.x;
    const int qb    = blockIdx.y;
    const int head  = blockIdx.z;
    const int kbase = chunk * KCH;

    {
        const int row  = t >> 1;
        const int half = (t & 1) * 8;
        const __hip_bfloat16* src = qkv + (size_t)(kbase + row) * 384 + head * 16 + half;
        #pragma unroll
        for (int j = 0; j < 8; ++j)
            Ks[row * 16 + half + j] = __bfloat162float(src[128 + j]);
        #pragma unroll
        for (int j = 0; j < 8; ++j)
            Vs[row * 16 + half + j] = __bfloat162float(src[256 + j]);
    }

    const int qrow = qb * 256 + t;
    float q[16];
    {
        const __hip_bfloat16* qp = qkv + (size_t)qrow * 384 + head * 16;
        #pragma unroll
        for (int d = 0; d < 16; ++d)
            q[d] = __bfloat162float(qp[d]) * 0.25f;
    }
    __syncthreads();

    float m = -INFINITY, l = 0.f;
    float O[16];
    #pragma unroll
    for (int d = 0; d < 16; ++d) O[d] = 0.f;

    for (int j0 = 0; j0 < KCH; j0 += 8) {
        float s[8];
        #pragma unroll
        for (int jj = 0; jj < 8; ++jj) {
            const float* kr = &Ks[(j0 + jj) * 16];
            float a = 0.f;
            #pragma unroll
            for (int d = 0; d < 16; d += 4) {
                float4 kv = *reinterpret_cast<const float4*>(kr + d);
                a += q[d] * kv.x + q[d + 1] * kv.y + q[d + 2] * kv.z + q[d + 3] * kv.w;
            }
            s[jj] = a;
        }
        float bm = s[0];
        #pragma unroll
        for (int jj = 1; jj < 8; ++jj) bm = fmaxf(bm, s[jj]);
        const float mn = fmaxf(m, bm);
        const float corr = __expf(m - mn);
        m = mn;
        l *= corr;
        #pragma unroll
        for (int d = 0; d < 16; ++d) O[d] *= corr;
        #pragma unroll
        for (int jj = 0; jj < 8; ++jj) {
            const float p = __expf(s[jj] - m);
            l += p;
            const float* vr = &Vs[(j0 + jj) * 16];
            #pragma unroll
            for (int d = 0; d < 16; ++d) O[d] += p * vr[d];
        }
    }

    const int pidx = ((chunk * H_HEADS + head) << 10) + qrow;
    pm[pidx] = m;
    pl[pidx] = l;
    #pragma unroll
    for (int d = 0; d < 16; d += 4) {
        float4 v = make_float4(O[d], O[d + 1], O[d + 2], O[d + 3]);
        *reinterpret_cast<float4*>(&po[(size_t)pidx * 16 + d]) = v;
    }
}

// combine partials -> attn_bf [S, D] (bf16)
__global__ __launch_bounds__(256) void attn_comb_kernel(
    const float* __restrict__ pm, const float* __restrict__ pl,
    const float* __restrict__ po, __hip_bfloat16* __restrict__ o)
{
    const int gid  = blockIdx.x * 256 + threadIdx.x;   // 0..8191
    const int head = gid >> 10;
    const int row  = gid & 1023;

    float mg = -INFINITY;
    #pragma unroll
    for (int c = 0; c < KSPLIT; ++c)
        mg = fmaxf(mg, pm[((c * H_HEADS + head) << 10) + row]);

    float lg = 0.f;
    float O[16];
    #pragma unroll
    for (int d = 0; d < 16; ++d) O[d] = 0.f;

    #pragma unroll
    for (int c = 0; c < KSPLIT; ++c) {
        const int pidx = ((c * H_HEADS + head) << 10) + row;
        const float w = __expf(pm[pidx] - mg);
        lg += pl[pidx] * w;
        #pragma unroll
        for (int d = 0; d < 16; d += 4) {
            float4 v = *reinterpret_cast<const float4*>(&po[(size_t)pidx * 16 + d]);
            O[d] += w * v.x; O[d + 1] += w * v.y;
            O[d + 2] += w * v.z; O[d + 3] += w * v.w;
        }
    }

    const float inv = 1.f / lg;
    __hip_bfloat16* op = o + (size_t)row * D_DIM + head * 16;
    #pragma unroll
    for (int d = 0; d < 16; ++d)
        op[d] = __float2bfloat16(O[d] * inv);
}

__global__ void zero_kernel(float* __restrict__ p, int n)
{
    const int i = blockIdx.x * blockDim.x + threadIdx.x;
    if (i < n) p[i] = 0.0f;
}

// ---------------------------------------------------------------------------
// Host launch
// ---------------------------------------------------------------------------
extern "C" void kernel_launch(void* const* d_in, const int* in_sizes, int n_in,
                              void* d_out, int out_size, void* d_ws, size_t ws_size,
                              hipStream_t stream)
{
    const int*   shot    = (const int*)  d_in[0];
    const int*   cam     = (const int*)  d_in[1];
    const int*   light   = (const int*)  d_in[2];
    const int*   tone    = (const int*)  d_in[3];
    const int*   rhythm  = (const int*)  d_in[4];
    const int*   trans   = (const int*)  d_in[5];
    const float* motion  = (const float*)d_in[6];
    const float* focus   = (const float*)d_in[7];
    const float* E_shot  = (const float*)d_in[8];
    const float* E_cam   = (const float*)d_in[9];
    const float* E_light = (const float*)d_in[10];
    const float* E_tone  = (const float*)d_in[11];
    const float* E_rhyth = (const float*)d_in[12];
    const float* E_trans = (const float*)d_in[13];
    const float* W_m1    = (const float*)d_in[14];
    const float* b_m1    = (const float*)d_in[15];
    const float* W_m2    = (const float*)d_in[16];
    const float* b_m2    = (const float*)d_in[17];
    const float* W_f     = (const float*)d_in[18];
    const float* b_f     = (const float*)d_in[19];
    const float* pos     = (const float*)d_in[20];
    const float* Wqkv    = (const float*)d_in[21];
    const float* bqkv    = (const float*)d_in[22];
    const float* Wo      = (const float*)d_in[23];
    const float* bo      = (const float*)d_in[24];
    const float* W1      = (const float*)d_in[25];
    const float* b1      = (const float*)d_in[26];
    const float* W2      = (const float*)d_in[27];
    const float* b2      = (const float*)d_in[28];
    const float* ln1_g   = (const float*)d_in[29];
    const float* ln1_b   = (const float*)d_in[30];
    const float* ln2_g   = (const float*)d_in[31];
    const float* ln2_b   = (const float*)d_in[32];
    const float* W_out   = (const float*)d_in[33];
    const float* b_out   = (const float*)d_in[34];

    float* out = (float*)d_out;

    // workspace layout (f32 region then bf16 region)
    float* ws = (float*)d_ws;
    float* x  = ws;                                // 131072
    float* pm = x  + S_LEN * D_DIM;                // 65536
    float* pl = pm + KSPLIT * H_HEADS * S_LEN;     // 65536
    float* po = pl + KSPLIT * H_HEADS * S_LEN;     // 1048576
    float* P  = po + KSPLIT * H_HEADS * S_LEN * 16;  // 1048576 (gemm partials)
    __hip_bfloat16* bfb = (__hip_bfloat16*)(P + KSPLIT * S_LEN * D_DIM);
    __hip_bfloat16* wqkv_bf = bfb;                    // [4][384][128]
    __hip_bfloat16* wo_bf   = wqkv_bf + 196608;       // [4][128][128]
    __hip_bfloat16* w1_bf   = wo_bf   + 65536;        // [4][2048][128]
    __hip_bfloat16* w2_bf   = w1_bf   + 1048576;      // [4][128][2048]
    __hip_bfloat16* wout_bf = w2_bf   + 1048576;      // [768][128]
    __hip_bfloat16* x_bf    = wout_bf + 98304;        // [1024][128]
    __hip_bfloat16* qkv_bf  = x_bf    + 131072;       // [1024][384]
    __hip_bfloat16* attn_bf = qkv_bf  + 393216;       // [1024][128]
    __hip_bfloat16* hbuf_bf = attn_bf + 131072;       // [1024][2048]

    embed_kernel<<<S_LEN, 128, 0, stream>>>(
        shot, cam, light, tone, rhythm, trans, motion, focus,
        E_shot, E_cam, E_light, E_tone, E_rhyth, E_trans,
        W_m1, b_m1, W_m2, b_m2, W_f, b_f, pos, x, x_bf);

    wconv_kernel<<<2400, 256, 0, stream>>>(Wqkv, Wo, W1, W2, W_out, bfb);

    for (int i = 0; i < L_LAYERS; ++i) {
        const __hip_bfloat16* Wqkv_i = wqkv_bf + (size_t)i * 3 * D_DIM * D_DIM;
        const __hip_bfloat16* Wo_i   = wo_bf   + (size_t)i * D_DIM * D_DIM;
        const __hip_bfloat16* W1_i   = w1_bf   + (size_t)i * FF_DIM * D_DIM;
        const __hip_bfloat16* W2_i   = w2_bf   + (size_t)i * D_DIM * FF_DIM;
        const float* bqkv_i = bqkv + (size_t)i * 3 * D_DIM;
        const float* bo_i   = bo   + (size_t)i * D_DIM;
        const float* b1_i   = b1   + (size_t)i * FF_DIM;
        const float* b2_i   = b2   + (size_t)i * D_DIM;

        // qkv = x @ Wqkv^T + bqkv -> bf16 [1024, 384]   grid 192 blocks
        gemm_mfma_kernel<0, 1><<<dim3(384 / 64, S_LEN / 32), 256, 0, stream>>>(
            x_bf, Wqkv_i, bqkv_i, qkv_bf, nullptr, 384, 128);

        // attention -> bf16 [1024, 128]
        attn_part_kernel<<<dim3(KSPLIT, S_LEN / 256, H_HEADS), 256, 0, stream>>>(
            qkv_bf, pm, pl, po);
        attn_comb_kernel<<<dim3(S_LEN * H_HEADS / 256), 256, 0, stream>>>(
            pm, pl, po, attn_bf);

        // Wo: split-K=2 partials (grid 128 blocks) + fused add+LN
        gemm_sk_kernel<<<dim3(2, S_LEN / 32, 2), 256, 0, stream>>>(
            attn_bf, Wo_i, P, D_DIM, 128, 64);
        add_ln_kernel<<<S_LEN, 128, 0, stream>>>(
            x, x_bf, P, 2, S_LEN * D_DIM, bo_i,
            ln1_g + (size_t)i * D_DIM, ln1_b + (size_t)i * D_DIM);

        // h = relu(x @ W1^T + b1) -> bf16 [1024, 2048]   grid 1024 blocks
        gemm_mfma_kernel<1, 1><<<dim3(FF_DIM / 64, S_LEN / 32), 256, 0, stream>>>(
            x_bf, W1_i, b1_i, hbuf_bf, nullptr, FF_DIM, 128);

        // FF2: split-K=8 partials (grid 512 blocks) + fused add+LN
        gemm_sk_kernel<<<dim3(2, S_LEN / 32, KSPLIT), 256, 0, stream>>>(
            hbuf_bf, W2_i, P, D_DIM, FF_DIM, FF_DIM / KSPLIT);
        add_ln_kernel<<<S_LEN, 128, 0, stream>>>(
            x, x_bf, P, KSPLIT, S_LEN * D_DIM, b2_i,
            ln2_g + (size_t)i * D_DIM, ln2_b + (size_t)i * D_DIM);
    }

    // cond = x @ W_out^T + b_out -> f32 [1024, 768]   grid 384 blocks
    gemm_mfma_kernel<0, 0><<<dim3(HID_DIM / 64, S_LEN / 32), 256, 0, stream>>>(
        x_bf, wout_bf, b_out, nullptr, out, HID_DIM, 128);

    // boundary_mask = zeros [1024]
    zero_kernel<<<1, 1024, 0, stream>>>(out + (size_t)S_LEN * HID_DIM, S_LEN);
}